// Round 1
// baseline (304.473 us; speedup 1.0000x reference)
//
#include <hip/hip_runtime.h>

#define E_TOTAL 1000000
#define NN 50000

typedef __attribute__((ext_vector_type(8))) short bf16x8;
typedef __attribute__((ext_vector_type(8))) __bf16 bfv8;
typedef __attribute__((ext_vector_type(4))) float f32x4;

__device__ __forceinline__ bf16x8 cvt8(const float* __restrict__ p) {
  const float4 v0 = *reinterpret_cast<const float4*>(p);
  const float4 v1 = *reinterpret_cast<const float4*>(p + 4);
  bfv8 f;
  f[0] = (__bf16)v0.x; f[1] = (__bf16)v0.y; f[2] = (__bf16)v0.z; f[3] = (__bf16)v0.w;
  f[4] = (__bf16)v1.x; f[5] = (__bf16)v1.y; f[6] = (__bf16)v1.z; f[7] = (__bf16)v1.w;
  return __builtin_bit_cast(bf16x8, f);
}

__device__ __forceinline__ bf16x8 cvt8s(const float* __restrict__ p, float s) {
  const float4 v0 = *reinterpret_cast<const float4*>(p);
  const float4 v1 = *reinterpret_cast<const float4*>(p + 4);
  bfv8 f;
  f[0] = (__bf16)(v0.x * s); f[1] = (__bf16)(v0.y * s); f[2] = (__bf16)(v0.z * s); f[3] = (__bf16)(v0.w * s);
  f[4] = (__bf16)(v1.x * s); f[5] = (__bf16)(v1.y * s); f[6] = (__bf16)(v1.z * s); f[7] = (__bf16)(v1.w * s);
  return __builtin_bit_cast(bf16x8, f);
}

__global__ void count_kernel(const int* __restrict__ ei, float* __restrict__ counts) {
  int i = blockIdx.x * blockDim.x + threadIdx.x;
  if (i < E_TOTAL) atomicAdd(counts + ei[E_TOTAL + i], 1.0f);
}

// Each block: 256 threads = 4 waves; each wave: 4 tiles of 16 edges (64 edges).
// MFMA 16x16x32 bf16. A = edge features (direct from global, no LDS),
// B = W fragments preloaded in registers. Layer1->Layer2 transpose via
// wave-private LDS slab. Scatter via fp32 atomics into `sums` (= d_out).
__global__ __launch_bounds__(256, 1) void edge_kernel(
    const float* __restrict__ x, const int* __restrict__ ei,
    const float* __restrict__ ea, const float* __restrict__ W1,
    const float* __restrict__ b1, const float* __restrict__ W2,
    const float* __restrict__ b2, float* __restrict__ sums) {
  __shared__ ushort h_lds[4][16 * 72];
  const int tid = threadIdx.x;
  const int w = tid >> 6, l = tid & 63;
  const int c = l & 15, g = l >> 4;

  // Preload W1 (128x64) fragments: B[k][n], lane holds k=s*32+g*8+e, n=t*16+c
  bf16x8 w1f[4][4];
#pragma unroll
  for (int s = 0; s < 4; ++s)
#pragma unroll
    for (int t = 0; t < 4; ++t) {
      const float* wp = W1 + (s * 32 + g * 8) * 64 + t * 16 + c;
      bfv8 f;
#pragma unroll
      for (int e = 0; e < 8; ++e) f[e] = (__bf16)wp[e * 64];
      w1f[s][t] = __builtin_bit_cast(bf16x8, f);
    }
  // Preload W2 (64x64) fragments
  bf16x8 w2f[2][4];
#pragma unroll
  for (int s = 0; s < 2; ++s)
#pragma unroll
    for (int t = 0; t < 4; ++t) {
      const float* wp = W2 + (s * 32 + g * 8) * 64 + t * 16 + c;
      bfv8 f;
#pragma unroll
      for (int e = 0; e < 8; ++e) f[e] = (__bf16)wp[e * 64];
      w2f[s][t] = __builtin_bit_cast(bf16x8, f);
    }
  float b1v[4], b2v[4];
#pragma unroll
  for (int t = 0; t < 4; ++t) {
    b1v[t] = b1[t * 16 + c];
    b2v[t] = b2[t * 16 + c];
  }

  ushort* hl = h_lds[w];
  const int ebase0 = blockIdx.x * 256 + w * 64;
#pragma unroll 1
  for (int it = 0; it < 4; ++it) {
    const int eb = ebase0 + it * 16;
    if (eb >= E_TOTAL) break;  // wave-uniform
    const int my_e = eb + c;
    const int xr = ei[my_e];
    const float* xp = x + (long)xr * 64 + g * 8;
    const float* ap = ea + (long)my_e * 64 + g * 8;
    // A fragments: feat[row=c][k=(g*8..g*8+7)+32*s], cols 0-63 = x, 64-127 = ea
    bf16x8 a0 = cvt8(xp);
    bf16x8 a1 = cvt8(xp + 32);
    bf16x8 a2 = cvt8(ap);
    bf16x8 a3 = cvt8(ap + 32);

    f32x4 acc[4];
#pragma unroll
    for (int t = 0; t < 4; ++t) acc[t] = (f32x4){0.f, 0.f, 0.f, 0.f};
#pragma unroll
    for (int t = 0; t < 4; ++t) {
      acc[t] = __builtin_amdgcn_mfma_f32_16x16x32_bf16(a0, w1f[0][t], acc[t], 0, 0, 0);
      acc[t] = __builtin_amdgcn_mfma_f32_16x16x32_bf16(a1, w1f[1][t], acc[t], 0, 0, 0);
      acc[t] = __builtin_amdgcn_mfma_f32_16x16x32_bf16(a2, w1f[2][t], acc[t], 0, 0, 0);
      acc[t] = __builtin_amdgcn_mfma_f32_16x16x32_bf16(a3, w1f[3][t], acc[t], 0, 0, 0);
    }
    // bias + ReLU, D-layout (row=4g+r, col=t*16+c) -> LDS row-major [16][72]
#pragma unroll
    for (int t = 0; t < 4; ++t)
#pragma unroll
      for (int r = 0; r < 4; ++r) {
        float hv = fmaxf(acc[t][r] + b1v[t], 0.f);
        __bf16 hb = (__bf16)hv;
        hl[(g * 4 + r) * 72 + t * 16 + c] = __builtin_bit_cast(unsigned short, hb);
      }
    __builtin_amdgcn_wave_barrier();
    // Layer 2: A frag = h[row=c][k=s*32+g*8+e]
    bf16x8 h0 = *reinterpret_cast<const bf16x8*>(hl + c * 72 + g * 8);
    bf16x8 h1 = *reinterpret_cast<const bf16x8*>(hl + c * 72 + 32 + g * 8);
    f32x4 o[4];
#pragma unroll
    for (int t = 0; t < 4; ++t) o[t] = (f32x4){0.f, 0.f, 0.f, 0.f};
#pragma unroll
    for (int t = 0; t < 4; ++t) {
      o[t] = __builtin_amdgcn_mfma_f32_16x16x32_bf16(h0, w2f[0][t], o[t], 0, 0, 0);
      o[t] = __builtin_amdgcn_mfma_f32_16x16x32_bf16(h1, w2f[1][t], o[t], 0, 0, 0);
    }
    __builtin_amdgcn_wave_barrier();  // protect hl reuse next iteration
    // Scatter-add: value at (edge m=4g+r, channel t*16+c)
#pragma unroll
    for (int r = 0; r < 4; ++r) {
      const int node = ei[E_TOTAL + eb + g * 4 + r];
#pragma unroll
      for (int t = 0; t < 4; ++t)
        atomicAdd(sums + (long)node * 64 + t * 16 + c, o[t][r] + b2v[t]);
    }
  }
}

// Node MLP: feat = [x | sums/max(cnt,1) | u[batch]] (192) -> 64 -> 64.
// Reads sums from `out` rows it owns, overwrites them with the final output.
__global__ __launch_bounds__(256, 1) void node_kernel(
    const float* __restrict__ x, const int* __restrict__ batch,
    const float* __restrict__ u, const float* __restrict__ W3,
    const float* __restrict__ b3, const float* __restrict__ W4,
    const float* __restrict__ b4, const float* __restrict__ counts,
    float* __restrict__ out) {
  __shared__ ushort h_lds[4][16 * 72];
  const int tid = threadIdx.x;
  const int w = tid >> 6, l = tid & 63;
  const int c = l & 15, g = l >> 4;

  bf16x8 w3f[6][4];
#pragma unroll
  for (int s = 0; s < 6; ++s)
#pragma unroll
    for (int t = 0; t < 4; ++t) {
      const float* wp = W3 + (s * 32 + g * 8) * 64 + t * 16 + c;
      bfv8 f;
#pragma unroll
      for (int e = 0; e < 8; ++e) f[e] = (__bf16)wp[e * 64];
      w3f[s][t] = __builtin_bit_cast(bf16x8, f);
    }
  bf16x8 w4f[2][4];
#pragma unroll
  for (int s = 0; s < 2; ++s)
#pragma unroll
    for (int t = 0; t < 4; ++t) {
      const float* wp = W4 + (s * 32 + g * 8) * 64 + t * 16 + c;
      bfv8 f;
#pragma unroll
      for (int e = 0; e < 8; ++e) f[e] = (__bf16)wp[e * 64];
      w4f[s][t] = __builtin_bit_cast(bf16x8, f);
    }
  float b3v[4], b4v[4];
#pragma unroll
  for (int t = 0; t < 4; ++t) {
    b3v[t] = b3[t * 16 + c];
    b4v[t] = b4[t * 16 + c];
  }

  ushort* hl = h_lds[w];
  const int nbase0 = blockIdx.x * 256 + w * 64;
#pragma unroll 1
  for (int it = 0; it < 4; ++it) {
    const int nb = nbase0 + it * 16;
    if (nb >= NN) break;  // wave-uniform
    const int my_n = nb + c;
    const float* xp = x + (long)my_n * 64 + g * 8;
    const float* sp = out + (long)my_n * 64 + g * 8;
    const float* up = u + (long)batch[my_n] * 64 + g * 8;
    const float inv = 1.0f / fmaxf(counts[my_n], 1.0f);
    bf16x8 a0 = cvt8(xp);
    bf16x8 a1 = cvt8(xp + 32);
    bf16x8 a2 = cvt8s(sp, inv);
    bf16x8 a3 = cvt8s(sp + 32, inv);
    bf16x8 a4 = cvt8(up);
    bf16x8 a5 = cvt8(up + 32);

    f32x4 acc[4];
#pragma unroll
    for (int t = 0; t < 4; ++t) acc[t] = (f32x4){0.f, 0.f, 0.f, 0.f};
#pragma unroll
    for (int t = 0; t < 4; ++t) {
      acc[t] = __builtin_amdgcn_mfma_f32_16x16x32_bf16(a0, w3f[0][t], acc[t], 0, 0, 0);
      acc[t] = __builtin_amdgcn_mfma_f32_16x16x32_bf16(a1, w3f[1][t], acc[t], 0, 0, 0);
      acc[t] = __builtin_amdgcn_mfma_f32_16x16x32_bf16(a2, w3f[2][t], acc[t], 0, 0, 0);
      acc[t] = __builtin_amdgcn_mfma_f32_16x16x32_bf16(a3, w3f[3][t], acc[t], 0, 0, 0);
      acc[t] = __builtin_amdgcn_mfma_f32_16x16x32_bf16(a4, w3f[4][t], acc[t], 0, 0, 0);
      acc[t] = __builtin_amdgcn_mfma_f32_16x16x32_bf16(a5, w3f[5][t], acc[t], 0, 0, 0);
    }
#pragma unroll
    for (int t = 0; t < 4; ++t)
#pragma unroll
      for (int r = 0; r < 4; ++r) {
        float hv = fmaxf(acc[t][r] + b3v[t], 0.f);
        __bf16 hb = (__bf16)hv;
        hl[(g * 4 + r) * 72 + t * 16 + c] = __builtin_bit_cast(unsigned short, hb);
      }
    __builtin_amdgcn_wave_barrier();
    bf16x8 h0 = *reinterpret_cast<const bf16x8*>(hl + c * 72 + g * 8);
    bf16x8 h1 = *reinterpret_cast<const bf16x8*>(hl + c * 72 + 32 + g * 8);
    f32x4 o[4];
#pragma unroll
    for (int t = 0; t < 4; ++t) o[t] = (f32x4){0.f, 0.f, 0.f, 0.f};
#pragma unroll
    for (int t = 0; t < 4; ++t) {
      o[t] = __builtin_amdgcn_mfma_f32_16x16x32_bf16(h0, w4f[0][t], o[t], 0, 0, 0);
      o[t] = __builtin_amdgcn_mfma_f32_16x16x32_bf16(h1, w4f[1][t], o[t], 0, 0, 0);
    }
    __builtin_amdgcn_wave_barrier();
#pragma unroll
    for (int r = 0; r < 4; ++r) {
      const int nrow = nb + g * 4 + r;
#pragma unroll
      for (int t = 0; t < 4; ++t)
        out[(long)nrow * 64 + t * 16 + c] = o[t][r] + b4v[t];
    }
  }
}

extern "C" void kernel_launch(void* const* d_in, const int* in_sizes, int n_in,
                              void* d_out, int out_size, void* d_ws, size_t ws_size,
                              hipStream_t stream) {
  const float* x = (const float*)d_in[0];
  const int* ei = (const int*)d_in[1];
  const float* ea = (const float*)d_in[2];
  const float* u = (const float*)d_in[3];
  const int* batch = (const int*)d_in[4];
  const float* W1 = (const float*)d_in[5];
  const float* b1 = (const float*)d_in[6];
  const float* W2 = (const float*)d_in[7];
  const float* b2 = (const float*)d_in[8];
  const float* W3 = (const float*)d_in[9];
  const float* b3 = (const float*)d_in[10];
  const float* W4 = (const float*)d_in[11];
  const float* b4 = (const float*)d_in[12];
  float* out = (float*)d_out;       // doubles as the scatter-sum accumulator
  float* counts = (float*)d_ws;     // 50000 floats

  hipMemsetAsync(out, 0, (size_t)NN * 64 * sizeof(float), stream);
  hipMemsetAsync(counts, 0, (size_t)NN * sizeof(float), stream);

  count_kernel<<<(E_TOTAL + 255) / 256, 256, 0, stream>>>(ei, counts);
  edge_kernel<<<(E_TOTAL + 255) / 256, 256, 0, stream>>>(x, ei, ea, W1, b1, W2, b2, out);
  node_kernel<<<(NN + 255) / 256, 256, 0, stream>>>(x, batch, u, W3, b3, W4, b4, counts, out);
}